// Round 1
// baseline (419.169 us; speedup 1.0000x reference)
//
#include <hip/hip_runtime.h>

typedef short bf16x8 __attribute__((ext_vector_type(8)));
typedef float f32x4 __attribute__((ext_vector_type(4)));
typedef int   i32x4 __attribute__((ext_vector_type(4)));

#define INV_SQRT165 0.07784989441615349f
#define FINAL_SCALE 0.0032113081446662823f   /* sqrt(165)/4000 */

__device__ __forceinline__ unsigned short f2bf(float f) {
  unsigned int u = __builtin_bit_cast(unsigned int, f);
  unsigned int r = (u + 0x7FFFu + ((u >> 16) & 1u)) >> 16;
  return (unsigned short)r;
}

__device__ __forceinline__ void decode_i(int i, int& lv, int& rel) {
  if (i < 1)       { lv = 0; rel = i; }
  else if (i < 10) { lv = 1; rel = i - 1; }
  else if (i < 35) { lv = 2; rel = i - 10; }
  else if (i < 84) { lv = 3; rel = i - 35; }
  else             { lv = 4; rel = i - 84; }
}

// psi1[y*25+i] = sum_n Y[n,i]*w_s2[0,y,n] / sqrt(48)
__global__ void psi1_k(const float* __restrict__ Y, const float* __restrict__ w_s2,
                       float* __restrict__ psi1) {
  int t = blockIdx.x * 256 + threadIdx.x;
  if (t >= 400) return;
  int y = t / 25, i = t % 25;
  float s = 0.f;
  for (int n = 0; n < 48; n++) s += Y[n * 25 + i] * w_s2[y * 48 + n];
  psi1[t] = s * 0.14433756729740643f;
}

// psi2[ch*165+i] = sum_n D_kernel[n,i]*w_so3[ch,0,n] / sqrt(192)
__global__ void psi2_k(const float* __restrict__ Dk, const float* __restrict__ w_so3,
                       float* __restrict__ psi2) {
  int t = blockIdx.x * 256 + threadIdx.x;
  if (t >= 2640) return;
  int ch = t / 165, i = t % 165;
  float s = 0.f;
  for (int n = 0; n < 192; n++) s += Dk[n * 165 + i] * w_so3[ch * 192 + n];
  psi2[t] = s * 0.07216878364870323f;
}

// h1[(b*16+y)*192 + i] = bf16( x[b, l^2+m] * psi1[y, l^2+j] ), K-padded to 192
__global__ void h1_k(const float* __restrict__ x, const float* __restrict__ psi1,
                     unsigned short* __restrict__ h1) {
  int idx = blockIdx.x * 256 + threadIdx.x;   // < 6291456 exact
  int r = idx / 192, i = idx - r * 192;
  int b = r >> 4, y = r & 15;
  unsigned short out = 0;
  if (i < 165) {
    int lv, rel; decode_i(i, lv, rel);
    int d = 2 * lv + 1;
    int j = rel / d, m = rel - j * d;
    int xo = lv * lv;
    out = f2bf(x[b * 25 + xo + m] * psi1[y * 25 + xo + j]);
  }
  h1[idx] = out;
}

// d1[g*192+k] = bf16 D_act[g,k] (zero pad g>=4000, k>=165)  (4032 x 192)
__global__ void d1_k(const float* __restrict__ Da, unsigned short* __restrict__ d1) {
  int idx = blockIdx.x * 256 + threadIdx.x;   // < 774144 exact
  int g = idx / 192, k = idx - g * 192;
  float v = (g < 4000 && k < 165) ? Da[g * 165 + k] : 0.f;
  d1[idx] = f2bf(v);
}

// d2[n*4032+g] = bf16 D_act[g,n] (transposed; zero pad)  (176 x 4032)
__global__ void d2_k(const float* __restrict__ Da, unsigned short* __restrict__ d2) {
  int idx = blockIdx.x * 256 + threadIdx.x;   // < 709632 exact
  int n = idx / 4032, g = idx - n * 4032;
  float v = (n < 165 && g < 4000) ? Da[g * 165 + n] : 0.f;
  d2[idx] = f2bf(v);
}

// ewT[e*192+k] = bf16 eval_wigners[k,e] (zero pad k>=165)  (4608 x 192)
__global__ void ewt_k(const float* __restrict__ ew, unsigned short* __restrict__ ewT) {
  int idx = blockIdx.x * 256 + threadIdx.x;   // < 884736 exact
  int e = idx / 192, k = idx - e * 192;
  float v = (k < 165) ? ew[k * 4608 + e] : 0.f;
  ewT[idx] = f2bf(v);
}

// Fused: S = relu(H . D_act^T / sqrt165) ; O = S . D_act * sqrt165/4000 ;
// then so3_to_so3 epilogue -> harmonics (fp32 to d_out, bf16 copy to ws).
// Block = 64 rows (4 waves x 16 rows = 4 batch elems x 16 channels), g-chunks of 64.
__global__ __launch_bounds__(256, 2) void fused_mlp_k(
    const unsigned short* __restrict__ h1,
    const unsigned short* __restrict__ d1,
    const unsigned short* __restrict__ d2,
    const float* __restrict__ psi2,
    float* __restrict__ harm_out,
    unsigned short* __restrict__ harmb)
{
  // lds1: 64x200 shorts @0 ; lds2: 176x72 shorts @12800 ; S: 4 x 16x72 shorts @25472
  __shared__ __align__(16) short smem[30080];
  const int tid = threadIdx.x;
  const int l = tid & 63, w = tid >> 6;
  const int ln = l & 15, q = l >> 4;
  const int m0 = blockIdx.x * 64 + w * 16;

  bf16x8 a1[6];
  {
    const short* hp = (const short*)h1 + (m0 + ln) * 192 + q * 8;
#pragma unroll
    for (int kf = 0; kf < 6; kf++) a1[kf] = *(const bf16x8*)(hp + kf * 32);
  }
  f32x4 o[11];
#pragma unroll
  for (int nf = 0; nf < 11; nf++) o[nf] = (f32x4){0.f, 0.f, 0.f, 0.f};

  short* ldsS = &smem[25472 + w * (16 * 72)];

  for (int ci = 0; ci < 63; ci++) {
    const int g0 = ci * 64;
    {
      const short* src = (const short*)d1 + g0 * 192;
#pragma unroll
      for (int it = 0; it < 6; it++) {
        int idx = it * 256 + tid;          // < 1536 exact
        int g = idx / 24, c = idx % 24;
        *(i32x4*)(&smem[g * 200 + c * 8]) = *(const i32x4*)(src + g * 192 + c * 8);
      }
    }
    {
      const short* src = (const short*)d2 + g0;
#pragma unroll
      for (int it = 0; it < 6; it++) {
        int idx = it * 256 + tid;
        if (idx < 1408) {                  // 176*8
          int n = idx >> 3, c = idx & 7;
          *(i32x4*)(&smem[12800 + n * 72 + c * 8]) = *(const i32x4*)(src + n * 4032 + c * 8);
        }
      }
    }
    __syncthreads();
    // GEMM1 + relu + S store (C/D layout -> row-major LDS, per-wave region)
#pragma unroll
    for (int gf = 0; gf < 4; gf++) {
      f32x4 acc = (f32x4){0.f, 0.f, 0.f, 0.f};
#pragma unroll
      for (int kf = 0; kf < 6; kf++) {
        bf16x8 bfr = *(const bf16x8*)(&smem[(gf * 16 + ln) * 200 + kf * 32 + q * 8]);
        acc = __builtin_amdgcn_mfma_f32_16x16x32_bf16(a1[kf], bfr, acc, 0, 0, 0);
      }
#pragma unroll
      for (int r = 0; r < 4; r++) {
        float v = acc[r];
        v = v > 0.f ? v * INV_SQRT165 : 0.f;
        ldsS[(q * 4 + r) * 72 + gf * 16 + ln] = (short)f2bf(v);
      }
    }
    __syncthreads();
    // GEMM2: O += S . D_act  (A-frags from LDS S, B-frags from lds2 = D_act^T rows)
#pragma unroll
    for (int kf2 = 0; kf2 < 2; kf2++) {
      bf16x8 a2 = *(const bf16x8*)(ldsS + ln * 72 + kf2 * 32 + q * 8);
#pragma unroll
      for (int nf = 0; nf < 11; nf++) {
        bf16x8 b2 = *(const bf16x8*)(&smem[12800 + (nf * 16 + ln) * 72 + kf2 * 32 + q * 8]);
        o[nf] = __builtin_amdgcn_mfma_f32_16x16x32_bf16(a2, b2, o[nf], 0, 0, 0);
      }
    }
    __syncthreads();
  }

  // Epilogue: dump O (scaled) to LDS (16 ch x 180 stride per wave), then so3_to_so3.
  float* ow = (float*)smem + w * (16 * 180);
#pragma unroll
  for (int nf = 0; nf < 11; nf++)
#pragma unroll
    for (int r = 0; r < 4; r++)
      ow[(q * 4 + r) * 180 + nf * 16 + ln] = o[nf][r] * FINAL_SCALE;
  __syncthreads();

  const int b = blockIdx.x * 4 + w;
  for (int ii = l; ii < 192; ii += 64) {
    if (ii < 165) {
      int lv, rel; decode_i(ii, lv, rel);
      int d = 2 * lv + 1;
      int off = ii - rel;
      int v = rel / d, m = rel - v * d;
      float s = 0.f;
      for (int ch = 0; ch < 16; ch++) {
        const float* row = ow + ch * 180 + off;
        const float* p2  = psi2 + ch * 165 + off;
        for (int u = 0; u < d; u++) s += row[u * d + m] * p2[u * d + v];
      }
      s *= 0.25f * rsqrtf((float)d);   // 1/sqrt(16*d)
      harm_out[b * 165 + ii] = s;
      harmb[b * 192 + ii] = f2bf(s);
    } else {
      harmb[b * 192 + ii] = 0;
    }
  }
}

// logits[m, n] = sum_k harm_bf16[m,k] * ewT[n,k]   (2048 x 4608, K=192)
__global__ __launch_bounds__(256, 2) void eval_k(
    const unsigned short* __restrict__ harmb,
    const unsigned short* __restrict__ ewT,
    float* __restrict__ logits)
{
  __shared__ __align__(16) short lb[128 * 200];
  const int tid = threadIdx.x;
  const int l = tid & 63, w = tid >> 6;
  const int ln = l & 15, q = l >> 4;
  const int n0 = blockIdx.x * 128;
  const int m0 = blockIdx.y * 64 + w * 16;

  bf16x8 a[6];
  {
    const short* hp = (const short*)harmb + (m0 + ln) * 192 + q * 8;
#pragma unroll
    for (int kf = 0; kf < 6; kf++) a[kf] = *(const bf16x8*)(hp + kf * 32);
  }
  {
    const short* src = (const short*)ewT + n0 * 192;
#pragma unroll
    for (int it = 0; it < 12; it++) {
      int idx = it * 256 + tid;            // < 3072 exact
      int n = idx / 24, c = idx % 24;
      *(i32x4*)(&lb[n * 200 + c * 8]) = *(const i32x4*)(src + n * 192 + c * 8);
    }
  }
  __syncthreads();

  f32x4 o[8];
#pragma unroll
  for (int nf = 0; nf < 8; nf++) o[nf] = (f32x4){0.f, 0.f, 0.f, 0.f};
#pragma unroll
  for (int kf = 0; kf < 6; kf++) {
#pragma unroll
    for (int nf = 0; nf < 8; nf++) {
      bf16x8 bfr = *(const bf16x8*)(&lb[(nf * 16 + ln) * 200 + kf * 32 + q * 8]);
      o[nf] = __builtin_amdgcn_mfma_f32_16x16x32_bf16(a[kf], bfr, o[nf], 0, 0, 0);
    }
  }
#pragma unroll
  for (int nf = 0; nf < 8; nf++)
#pragma unroll
    for (int r = 0; r < 4; r++)
      logits[(m0 + q * 4 + r) * 4608 + n0 + nf * 16 + ln] = o[nf][r];
}

// In-place row softmax over 4608 cols, one block per row.
__global__ __launch_bounds__(256) void softmax_k(float* __restrict__ probs) {
  float* p = probs + (size_t)blockIdx.x * 4608;
  const int tid = threadIdx.x;
  const int l = tid & 63, w = tid >> 6;
  float v[18];
  float mx = -3.4e38f;
#pragma unroll
  for (int i = 0; i < 18; i++) { v[i] = p[i * 256 + tid]; mx = fmaxf(mx, v[i]); }
#pragma unroll
  for (int off = 32; off >= 1; off >>= 1) mx = fmaxf(mx, __shfl_xor(mx, off));
  __shared__ float sm[4], ss[4];
  if (l == 0) sm[w] = mx;
  __syncthreads();
  mx = fmaxf(fmaxf(sm[0], sm[1]), fmaxf(sm[2], sm[3]));
  float s = 0.f;
#pragma unroll
  for (int i = 0; i < 18; i++) { v[i] = __expf(v[i] - mx); s += v[i]; }
#pragma unroll
  for (int off = 32; off >= 1; off >>= 1) s += __shfl_xor(s, off);
  if (l == 0) ss[w] = s;
  __syncthreads();
  s = ss[0] + ss[1] + ss[2] + ss[3];
  float inv = 1.f / s;
#pragma unroll
  for (int i = 0; i < 18; i++) p[i * 256 + tid] = v[i] * inv;
}

// 5th-largest value (with multiplicity) of probs row 0, via 5x argmax+knockout.
__global__ __launch_bounds__(256) void fifth_k(const float* __restrict__ p0,
                                               float* __restrict__ fifth) {
  __shared__ float buf[4608];
  __shared__ float wv[4]; __shared__ int wi[4];
  __shared__ float bestv; __shared__ int besti;
  const int tid = threadIdx.x;
  const int l = tid & 63, w = tid >> 6;
  for (int i = tid; i < 4608; i += 256) buf[i] = p0[i];
  __syncthreads();
  float ff = 0.f;
  for (int it = 0; it < 5; it++) {
    float bm = -1.f; int bi = 0;
    for (int i = tid; i < 4608; i += 256) {
      float x = buf[i];
      if (x > bm) { bm = x; bi = i; }
    }
    for (int off = 32; off >= 1; off >>= 1) {
      float ov = __shfl_xor(bm, off); int oi = __shfl_xor(bi, off);
      if (ov > bm) { bm = ov; bi = oi; }
    }
    if (l == 0) { wv[w] = bm; wi[w] = bi; }
    __syncthreads();
    if (tid == 0) {
      float B = wv[0]; int I = wi[0];
      for (int k = 1; k < 4; k++) if (wv[k] > B) { B = wv[k]; I = wi[k]; }
      bestv = B; besti = I;
      buf[I] = -1.f;       // remove exactly one instance (duplicate-safe)
    }
    __syncthreads();
    ff = bestv;
    __syncthreads();
  }
  if (tid == 0) *fifth = ff;
}

__global__ void thresh_k(f32x4* __restrict__ p, const float* __restrict__ fifth) {
  int i = blockIdx.x * 256 + threadIdx.x;   // 9216*256 = 2359296 exact
  float t = *fifth;
  f32x4 v = p[i];
#pragma unroll
  for (int k = 0; k < 4; k++) v[k] = (v[k] < t) ? 0.f : v[k];
  p[i] = v;
}

extern "C" void kernel_launch(void* const* d_in, const int* in_sizes, int n_in,
                              void* d_out, int out_size, void* d_ws, size_t ws_size,
                              hipStream_t stream) {
  const float* x     = (const float*)d_in[0];
  const float* w_s2  = (const float*)d_in[1];
  const float* Y     = (const float*)d_in[2];
  const float* w_so3 = (const float*)d_in[3];
  const float* Dk    = (const float*)d_in[4];
  const float* Da    = (const float*)d_in[5];
  const float* ew    = (const float*)d_in[6];

  float* out = (float*)d_out;
  float* harm_out = out;                 // 2048*165
  float* probs = out + 337920;           // 2048*4608

  char* ws = (char*)d_ws;
  float* psi1  = (float*)(ws + 0);                      // 1600 B
  float* psi2  = (float*)(ws + 2048);                   // 10560 B
  float* fifth = (float*)(ws + 12800);                  // 4 B
  unsigned short* h1    = (unsigned short*)(ws + 13056);     // 12,582,912 B
  unsigned short* d1    = (unsigned short*)(ws + 12595968);  // 1,548,288 B
  unsigned short* d2    = (unsigned short*)(ws + 14144256);  // 1,419,264 B
  unsigned short* ewT   = (unsigned short*)(ws + 15563520);  // 1,769,472 B
  unsigned short* harmb = (unsigned short*)(ws + 17332992);  // 786,432 B

  psi1_k<<<2, 256, 0, stream>>>(Y, w_s2, psi1);
  psi2_k<<<11, 256, 0, stream>>>(Dk, w_so3, psi2);
  h1_k<<<24576, 256, 0, stream>>>(x, psi1, h1);
  d1_k<<<3024, 256, 0, stream>>>(Da, d1);
  d2_k<<<2772, 256, 0, stream>>>(Da, d2);
  ewt_k<<<3456, 256, 0, stream>>>(ew, ewT);
  fused_mlp_k<<<512, 256, 0, stream>>>(h1, d1, d2, psi2, harm_out, harmb);
  eval_k<<<dim3(36, 32), 256, 0, stream>>>(harmb, ewT, probs);
  softmax_k<<<2048, 256, 0, stream>>>(probs);
  fifth_k<<<1, 256, 0, stream>>>(probs, fifth);
  thresh_k<<<9216, 256, 0, stream>>>((f32x4*)probs, fifth);
}

// Round 2
// 319.107 us; speedup vs baseline: 1.3136x; 1.3136x over previous
//
#include <hip/hip_runtime.h>
#include <hip/hip_bf16.h>

typedef short bf16x8 __attribute__((ext_vector_type(8)));
typedef float f32x16 __attribute__((ext_vector_type(16)));
typedef int   i32x4  __attribute__((ext_vector_type(4)));

#define INV_SQRT165 0.07784989441615349f
#define FINAL_SCALE 0.0032113081446662823f   /* sqrt(165)/4000 */
#define ZERO16 ((f32x16){0.f,0.f,0.f,0.f,0.f,0.f,0.f,0.f,0.f,0.f,0.f,0.f,0.f,0.f,0.f,0.f})

__device__ __forceinline__ unsigned short f2bf(float f) {
  unsigned int u = __builtin_bit_cast(unsigned int, f);
  unsigned int r = (u + 0x7FFFu + ((u >> 16) & 1u)) >> 16;
  return (unsigned short)r;
}
__device__ __forceinline__ float bf2f(unsigned short h) {
  unsigned int u = ((unsigned int)h) << 16;
  return __builtin_bit_cast(float, u);
}
__device__ __forceinline__ unsigned int pack_bf2(float lo, float hi) {
  return ((unsigned int)f2bf(hi) << 16) | (unsigned int)f2bf(lo);
}

__device__ __forceinline__ void gl_lds16(const void* g, void* l) {
  __builtin_amdgcn_global_load_lds(
      (const __attribute__((address_space(1))) unsigned int*)(unsigned long long)g,
      (__attribute__((address_space(3))) unsigned int*)(unsigned int)(unsigned long long)l,
      16, 0, 0);
}

__device__ __forceinline__ void decode_i(int i, int& lv, int& rel) {
  if (i < 1)       { lv = 0; rel = i; }
  else if (i < 10) { lv = 1; rel = i - 1; }
  else if (i < 35) { lv = 2; rel = i - 10; }
  else if (i < 84) { lv = 3; rel = i - 35; }
  else             { lv = 4; rel = i - 84; }
}

// ---------------- pre-pass kernels ----------------

__global__ void psi1_k(const float* __restrict__ Y, const float* __restrict__ w_s2,
                       float* __restrict__ psi1) {
  int t = blockIdx.x * 256 + threadIdx.x;
  if (t >= 400) return;
  int y = t / 25, i = t % 25;
  float s = 0.f;
  for (int n = 0; n < 48; n++) s += Y[n * 25 + i] * w_s2[y * 48 + n];
  psi1[t] = s * 0.14433756729740643f;
}

__global__ void psi2_k(const float* __restrict__ Dk, const float* __restrict__ w_so3,
                       float* __restrict__ psi2) {
  int t = blockIdx.x * 256 + threadIdx.x;
  if (t >= 2640) return;
  int ch = t / 165, i = t % 165;
  float s = 0.f;
  for (int n = 0; n < 192; n++) s += Dk[n * 165 + i] * w_so3[ch * 192 + n];
  psi2[t] = s * 0.07216878364870323f;
}

// h1pre[mt][kf][l][j] = H[mt*32 + (l&31)][kf*16 + (l>>5)*8 + j]  (1024 x 12 x 64 x 8)
__global__ void h1pre_k(const float* __restrict__ x, const float* __restrict__ psi1,
                        unsigned short* __restrict__ h1pre) {
  int idx = blockIdx.x * 256 + threadIdx.x;     // < 6291456 exact
  int mt = idx / 6144, r = idx - mt * 6144;
  int kf = r >> 9, r2 = r & 511;
  int l = r2 >> 3, j = r2 & 7;
  int m = mt * 32 + (l & 31);
  int k = kf * 16 + (l >> 5) * 8 + j;
  unsigned short out = 0;
  if (k < 165) {
    int b = m >> 4, y = m & 15;
    int lv, rel; decode_i(k, lv, rel);
    int d = 2 * lv + 1;
    int jj = rel / d, mm = rel - jj * d;
    int xo = lv * lv;
    out = f2bf(x[b * 25 + xo + mm] * psi1[y * 25 + xo + jj]);
  }
  h1pre[idx] = out;
}

// d1pre[ci][kf][l][j] = Dact[ci*32 + (l&31)][kf*16 + (l>>5)*8 + j]   (126 x 12 x 512)
__global__ void d1pre_k(const float* __restrict__ Da, unsigned short* __restrict__ d1pre) {
  int idx = blockIdx.x * 256 + threadIdx.x;     // < 774144 exact
  int ci = idx / 6144, r = idx - ci * 6144;
  int kf = r >> 9, r2 = r & 511;
  int l = r2 >> 3, j = r2 & 7;
  int g = ci * 32 + (l & 31);
  int k = kf * 16 + (l >> 5) * 8 + j;
  float v = (g < 4000 && k < 165) ? Da[g * 165 + k] : 0.f;
  d1pre[idx] = f2bf(v);
}

// d2pre[ci][nf][gk][l][j] = Dact[ci*32 + gk*16 + (l>>5)*8 + j][nf*32 + (l&31)]  (126 x 6 x 2 x 512)
__global__ void d2pre_k(const float* __restrict__ Da, unsigned short* __restrict__ d2pre) {
  int idx = blockIdx.x * 256 + threadIdx.x;     // < 774144 exact
  int ci = idx / 6144, r = idx - ci * 6144;
  int nf = r / 1024, r2 = r - nf * 1024;
  int gk = r2 >> 9, r3 = r2 & 511;
  int l = r3 >> 3, j = r3 & 7;
  int g = ci * 32 + gk * 16 + (l >> 5) * 8 + j;
  int n = nf * 32 + (l & 31);
  float v = (n < 165 && g < 4000) ? Da[g * 165 + n] : 0.f;
  d2pre[idx] = f2bf(v);
}

// ewpre[nt][kf][l][j] = ew[kf*16 + (l>>5)*8 + j][nt*32 + (l&31)]   (144 x 12 x 512)
__global__ void ewpre_k(const float* __restrict__ ew, unsigned short* __restrict__ ewpre) {
  int idx = blockIdx.x * 256 + threadIdx.x;     // < 884736 exact
  int nt = idx / 6144, r = idx - nt * 6144;
  int kf = r >> 9, r2 = r & 511;
  int l = r2 >> 3, j = r2 & 7;
  int k = kf * 16 + (l >> 5) * 8 + j;
  int n = nt * 32 + (l & 31);
  float v = (k < 165) ? ew[k * 4608 + n] : 0.f;
  ewpre[idx] = f2bf(v);
}

// ---------------- fused MLP + so3-linear ----------------
// Per block: M=128 rows (4 waves x 32). 126 g-chunks of 32.
// GEMM1: S^T[g32][m32] = Dtile(g x k) . H^T   (H frags double as B operand)
// GEMM2: O[m32][n192] += S[m32][g32] . Dact[g32][n]; S->A via half shfl-exchange.
// Single __syncthreads per chunk; tiles prefetched via global_load_lds (dbuf).
__global__ __launch_bounds__(256, 2) void fused_mlp_k(
    const unsigned short* __restrict__ h1pre,
    const unsigned short* __restrict__ d1pre,
    const unsigned short* __restrict__ d2pre,
    const float* __restrict__ psi2,
    float* __restrict__ harm_out,
    unsigned short* __restrict__ harmbpre)
{
  __shared__ __align__(16) unsigned char smem[49152];   // 2 x 24KB tile buffers
  const int tid = threadIdx.x;
  const int w = tid >> 6, l = tid & 63;
  const int hl = l >> 5, ln = l & 31;
  const int bx = blockIdx.x;

  // H fragments (12 k16-tiles), 32-shape A/B layout
  bf16x8 hfr[12];
  {
    const short* hp = (const short*)h1pre + (bx * 4 + w) * 6144 + l * 8;
#pragma unroll
    for (int kf = 0; kf < 12; kf++) hfr[kf] = *(const bf16x8*)(hp + kf * 512);
  }

  f32x16 o[6];
#pragma unroll
  for (int nf = 0; nf < 6; nf++) o[nf] = ZERO16;

  // prologue: prefetch chunk 0 -> buffer 0 (24 x 1KB blocks, 6 per wave)
#pragma unroll
  for (int i = 0; i < 6; i++) {
    int tb = w * 6 + i;
    const unsigned short* g = (tb < 12) ? (d1pre + tb * 512 + l * 8)
                                        : (d2pre + (tb - 12) * 512 + l * 8);
    gl_lds16(g, smem + tb * 1024);
  }

  for (int ci = 0; ci < 126; ci++) {
    __syncthreads();                       // drains vmcnt: chunk ci resident everywhere
    const int cb = (ci & 1) * 24576;
    if (ci + 1 < 126) {                    // prefetch ci+1 (lands before next barrier)
      const int nb = ((ci + 1) & 1) * 24576;
      const unsigned short* s1 = d1pre + (ci + 1) * 6144;
      const unsigned short* s2 = d2pre + (ci + 1) * 6144;
#pragma unroll
      for (int i = 0; i < 6; i++) {
        int tb = w * 6 + i;
        const unsigned short* g = (tb < 12) ? (s1 + tb * 512 + l * 8)
                                            : (s2 + (tb - 12) * 512 + l * 8);
        gl_lds16(g, smem + nb + tb * 1024);
      }
    }

    // GEMM1 (two independent accumulation chains)
    f32x16 c0 = ZERO16, c1 = ZERO16;
#pragma unroll
    for (int kf = 0; kf < 12; kf += 2) {
      bf16x8 aD0 = *(const bf16x8*)(smem + cb + kf * 1024 + l * 16);
      bf16x8 aD1 = *(const bf16x8*)(smem + cb + (kf + 1) * 1024 + l * 16);
      c0 = __builtin_amdgcn_mfma_f32_32x32x16_bf16(aD0, hfr[kf], c0, 0, 0, 0);
      c1 = __builtin_amdgcn_mfma_f32_32x32x16_bf16(aD1, hfr[kf + 1], c1, 0, 0, 0);
    }

    // relu + scale + pack to bf16 pairs (dword p = g-pair base (2p&3)+8*(p>>1)+4*hl)
    unsigned int dw[8];
#pragma unroll
    for (int p = 0; p < 8; p++) {
      float v0 = fmaxf((c0[2 * p]     + c1[2 * p])     * INV_SQRT165, 0.f);
      float v1 = fmaxf((c0[2 * p + 1] + c1[2 * p + 1]) * INV_SQRT165, 0.f);
      dw[p] = pack_bf2(v0, v1);
    }
    // cross-half exchange: build A-operand frags of S for GEMM2
    unsigned int r1 = __shfl_xor(hl ? dw[0] : dw[2], 32);
    unsigned int r2 = __shfl_xor(hl ? dw[1] : dw[3], 32);
    unsigned int r3 = __shfl_xor(hl ? dw[4] : dw[6], 32);
    unsigned int r4 = __shfl_xor(hl ? dw[5] : dw[7], 32);
    i32x4 a2i0, a2i1;
    if (hl == 0) {
      a2i0 = (i32x4){(int)dw[0], (int)dw[1], (int)r1, (int)r2};
      a2i1 = (i32x4){(int)dw[4], (int)dw[5], (int)r3, (int)r4};
    } else {
      a2i0 = (i32x4){(int)r1, (int)r2, (int)dw[2], (int)dw[3]};
      a2i1 = (i32x4){(int)r3, (int)r4, (int)dw[6], (int)dw[7]};
    }
    bf16x8 a2_0 = __builtin_bit_cast(bf16x8, a2i0);
    bf16x8 a2_1 = __builtin_bit_cast(bf16x8, a2i1);

    // GEMM2: 6 independent chains x 2 k-tiles
    const unsigned char* d2b = smem + cb + 12 * 1024;
#pragma unroll
    for (int gk = 0; gk < 2; gk++) {
      bf16x8 a2 = gk ? a2_1 : a2_0;
#pragma unroll
      for (int nf = 0; nf < 6; nf++) {
        bf16x8 b2 = *(const bf16x8*)(d2b + (nf * 2 + gk) * 1024 + l * 16);
        o[nf] = __builtin_amdgcn_mfma_f32_32x32x16_bf16(a2, b2, o[nf], 0, 0, 0);
      }
    }
  }

  // ---------------- epilogue: so3_to_so3 ----------------
  __syncthreads();
  // stage O (scaled, bf16) wave-locally: rows = m_local (32), stride 178
  unsigned short* ostage = (unsigned short*)smem + w * (32 * 178);
#pragma unroll
  for (int nf = 0; nf < 6; nf++) {
    int n = nf * 32 + ln;
    if (n < 176) {
#pragma unroll
      for (int r = 0; r < 16; r++) {
        int row = (r & 3) + 8 * (r >> 2) + 4 * hl;
        ostage[row * 178 + n] = f2bf(o[nf][r] * FINAL_SCALE);
      }
    }
  }
  __syncthreads();

  const int b0 = bx * 8;
  for (int ii = tid; ii < 1536; ii += 256) {
    int e = ii / 192, i = ii - e * 192;
    int bb = b0 + e;
    unsigned short* hb = harmbpre + (((bb >> 5) * 12 + (i >> 4)) << 9)
                       + ((i >> 3) & 1) * 256 + (bb & 31) * 8 + (i & 7);
    if (i < 165) {
      const unsigned short* row0 = (const unsigned short*)smem
                                 + (e >> 1) * (32 * 178) + (e & 1) * (16 * 178);
      int lv, rel; decode_i(i, lv, rel);
      int d = 2 * lv + 1;
      int off = i - rel;
      int v = rel / d, m = rel - v * d;
      float s = 0.f;
      for (int ch = 0; ch < 16; ch++) {
        const unsigned short* rw = row0 + ch * 178 + off;
        const float* p2 = psi2 + ch * 165 + off;
        for (int u = 0; u < d; u++) s += bf2f(rw[u * d + m]) * p2[u * d + v];
      }
      s *= 0.25f * rsqrtf((float)d);
      harm_out[bb * 165 + i] = s;
      *hb = f2bf(s);
    } else {
      *hb = 0;
    }
  }
}

// ---------------- eval GEMM: logits = harm . ew  (2048 x 4608, K=192) ----------------
__global__ __launch_bounds__(256) void eval_k(
    const unsigned short* __restrict__ harmbpre,
    const unsigned short* __restrict__ ewpre,
    float* __restrict__ logits)
{
  const int tid = threadIdx.x;
  const int w = tid >> 6, l = tid & 63;
  const int hl = l >> 5, ln = l & 31;
  const int mt = blockIdx.y * 4 + w;
  const int n0 = blockIdx.x * 192;

  bf16x8 a[12];
  const short* ap = (const short*)harmbpre + mt * 6144 + l * 8;
#pragma unroll
  for (int kf = 0; kf < 12; kf++) a[kf] = *(const bf16x8*)(ap + kf * 512);

  const short* bp = (const short*)ewpre + (blockIdx.x * 6) * 6144 + l * 8;
#pragma unroll
  for (int nf = 0; nf < 6; nf++) {
    f32x16 acc = ZERO16;
    const short* bpn = bp + nf * 6144;
#pragma unroll
    for (int kf = 0; kf < 12; kf++) {
      bf16x8 b = *(const bf16x8*)(bpn + kf * 512);
      acc = __builtin_amdgcn_mfma_f32_32x32x16_bf16(a[kf], b, acc, 0, 0, 0);
    }
    const int col = n0 + nf * 32 + ln;
#pragma unroll
    for (int r = 0; r < 16; r++) {
      int row = (r & 3) + 8 * (r >> 2) + 4 * hl;
      logits[(mt * 32 + row) * 4608 + col] = acc[r];
    }
  }
}

// ---------------- fifth-prob from row-0 logits (softmax arithmetic mirrors smthresh_k) --------
__global__ __launch_bounds__(256) void fifth_k(const float* __restrict__ logit0,
                                               float* __restrict__ fifth) {
  __shared__ float buf[4608];
  __shared__ float sm[4], ss[4];
  __shared__ float wv[4]; __shared__ int wi[4];
  __shared__ float gbest;
  const int tid = threadIdx.x;
  const int l = tid & 63, w = tid >> 6;
  float v[18];
  float mx = -3.4e38f;
#pragma unroll
  for (int i = 0; i < 18; i++) {
    v[i] = logit0[i * 256 + tid];
    buf[i * 256 + tid] = v[i];
    mx = fmaxf(mx, v[i]);
  }
#pragma unroll
  for (int off = 32; off >= 1; off >>= 1) mx = fmaxf(mx, __shfl_xor(mx, off));
  if (l == 0) sm[w] = mx;
  __syncthreads();
  mx = fmaxf(fmaxf(sm[0], sm[1]), fmaxf(sm[2], sm[3]));
  float s = 0.f;
#pragma unroll
  for (int i = 0; i < 18; i++) { v[i] = __expf(v[i] - mx); s += v[i]; }
#pragma unroll
  for (int off = 32; off >= 1; off >>= 1) s += __shfl_xor(s, off);
  if (l == 0) ss[w] = s;
  __syncthreads();
  s = ss[0] + ss[1] + ss[2] + ss[3];
  float inv = 1.f / s;

  float ff = 0.f;
  for (int it = 0; it < 5; it++) {
    float bm = -3.4e38f; int bi = 0;
    for (int i = tid; i < 4608; i += 256) {
      float xx = buf[i];
      if (xx > bm) { bm = xx; bi = i; }
    }
    for (int off = 32; off >= 1; off >>= 1) {
      float ov = __shfl_xor(bm, off); int oi = __shfl_xor(bi, off);
      if (ov > bm) { bm = ov; bi = oi; }
    }
    if (l == 0) { wv[w] = bm; wi[w] = bi; }
    __syncthreads();
    if (tid == 0) {
      float B = wv[0]; int I = wi[0];
      for (int k = 1; k < 4; k++) if (wv[k] > B) { B = wv[k]; I = wi[k]; }
      gbest = B;
      buf[I] = -3.4e38f;     // knock out exactly one instance (duplicate-safe)
    }
    __syncthreads();
    ff = gbest;
    __syncthreads();
  }
  if (tid == 0) *fifth = __expf(ff - mx) * inv;
}

// ---------------- fused softmax + threshold (in-place on logits->probs) ----------------
__global__ __launch_bounds__(256) void smthresh_k(float* __restrict__ probs,
                                                  const float* __restrict__ fifth) {
  float* p = probs + (size_t)blockIdx.x * 4608;
  const int tid = threadIdx.x;
  const int l = tid & 63, w = tid >> 6;
  __shared__ float sm[4], ss[4];
  float v[18];
  float mx = -3.4e38f;
#pragma unroll
  for (int i = 0; i < 18; i++) { v[i] = p[i * 256 + tid]; mx = fmaxf(mx, v[i]); }
#pragma unroll
  for (int off = 32; off >= 1; off >>= 1) mx = fmaxf(mx, __shfl_xor(mx, off));
  if (l == 0) sm[w] = mx;
  __syncthreads();
  mx = fmaxf(fmaxf(sm[0], sm[1]), fmaxf(sm[2], sm[3]));
  float s = 0.f;
#pragma unroll
  for (int i = 0; i < 18; i++) { v[i] = __expf(v[i] - mx); s += v[i]; }
#pragma unroll
  for (int off = 32; off >= 1; off >>= 1) s += __shfl_xor(s, off);
  if (l == 0) ss[w] = s;
  __syncthreads();
  s = ss[0] + ss[1] + ss[2] + ss[3];
  float inv = 1.f / s;
  float t = *fifth;
#pragma unroll
  for (int i = 0; i < 18; i++) {
    float pv = v[i] * inv;
    p[i * 256 + tid] = (pv < t) ? 0.f : pv;
  }
}

extern "C" void kernel_launch(void* const* d_in, const int* in_sizes, int n_in,
                              void* d_out, int out_size, void* d_ws, size_t ws_size,
                              hipStream_t stream) {
  const float* x     = (const float*)d_in[0];
  const float* w_s2  = (const float*)d_in[1];
  const float* Y     = (const float*)d_in[2];
  const float* w_so3 = (const float*)d_in[3];
  const float* Dk    = (const float*)d_in[4];
  const float* Da    = (const float*)d_in[5];
  const float* ew    = (const float*)d_in[6];

  float* out = (float*)d_out;
  float* harm_out = out;                 // 2048*165
  float* probs    = out + 337920;        // 2048*4608 (logits stored here first)

  char* ws = (char*)d_ws;
  float* psi1  = (float*)(ws + 0);                         // 1,600 B
  float* psi2  = (float*)(ws + 1600);                      // 10,560 B
  float* fifth = (float*)(ws + 12160);                     // 4 B
  unsigned short* h1pre    = (unsigned short*)(ws + 12224);      // 12,582,912 B
  unsigned short* d1pre    = (unsigned short*)(ws + 12595136);   // 1,548,288 B
  unsigned short* d2pre    = (unsigned short*)(ws + 14143424);   // 1,548,288 B
  unsigned short* ewpre    = (unsigned short*)(ws + 15691712);   // 1,769,472 B
  unsigned short* harmbpre = (unsigned short*)(ws + 17461184);   // 786,432 B  (end ~18.25 MB)

  psi1_k <<<2,    256, 0, stream>>>(Y, w_s2, psi1);
  psi2_k <<<11,   256, 0, stream>>>(Dk, w_so3, psi2);
  h1pre_k<<<24576,256, 0, stream>>>(x, psi1, h1pre);
  d1pre_k<<<3024, 256, 0, stream>>>(Da, d1pre);
  d2pre_k<<<3024, 256, 0, stream>>>(Da, d2pre);
  ewpre_k<<<3456, 256, 0, stream>>>(ew, ewpre);
  fused_mlp_k<<<256, 256, 0, stream>>>(h1pre, d1pre, d2pre, psi2, harm_out, harmbpre);
  eval_k<<<dim3(24, 16), 256, 0, stream>>>(harmbpre, ewpre, probs);
  fifth_k<<<1, 256, 0, stream>>>(probs, fifth);
  smthresh_k<<<2048, 256, 0, stream>>>(probs, fifth);
}